// Round 4
// baseline (148.638 us; speedup 1.0000x reference)
//
#include <hip/hip_runtime.h>

// Radon transform: data (1,1,512,512) f32, angles (256,) f32 -> out (1,1,256,512) f32.
// Block = (angle, 64-col x-chunk), 512 threads (8 waves). For each of 8 64-row
// y-chunks, the rotated patch's bbox (<=92x92) is staged into a SINGLE 35.8 KB LDS
// buffer (4 blocks/CU = 32 waves = HW max; round-3 showed occupancy is king) and
// bilinear-sampled. Staging is REGISTER-PIPELINED one chunk ahead (T14 async-STAGE
// split): chunk k+1's 16B segments are global_load_dwordx4'd into 5 f32x4 regs
// BEFORE sampling chunk k (latency hidden under the sample phase), then ds_written
// to LDS after the barrier. Neither barrier drains an in-flight global load (the
// round-1 structure exposed a full L2 round-trip per chunk at its second barrier).
// STRIDE 95/97 by sign(c) (compile-time): per-lane bank step |c +- s| in [1,1.414]
// -> ~conflict-free ds_read2_b32 pairs; packed v_pk_fma_f32 lerps; DDA coords.

#define HH 512
#define WW 512
#define NA 256
#define XC 64
#define NXC (WW / XC)          // 8 x-chunks
#define NW 8                   // waves per block
#define YC 64
#define NCH (HH / YC)          // 8 y-chunks
#define ROWS_MAX 92            // bbox rows <= 63(|s|+|c|)+3 <= 92
#define SMAX 97                // LDS row allocation stride (max of 95/97)
#define SEGW 23                // 16B segments per bbox row (23*16B = 92 dwords)
#define NSLOT 5                // ceil(92*23 / 512) prefetch segments per thread
#define PAD 112                // >= 256*sqrt(2)-256+2
#define PW (WW + 2 * PAD)      // 736
#define PH (HH + 2 * PAD)      // 736

typedef float f32x2 __attribute__((ext_vector_type(2)));
typedef float f32x4 __attribute__((ext_vector_type(4)));

__global__ __launch_bounds__(256) void pad_kernel(
    const float* __restrict__ img, float* __restrict__ P)
{
    const int c = blockIdx.x * 256 + threadIdx.x;
    const int r = blockIdx.y;
    if (c >= PW) return;
    const int gr = r - PAD, gc = c - PAD;
    float v = 0.0f;
    if ((unsigned)gr < (unsigned)HH && (unsigned)gc < (unsigned)WW)
        v = img[gr * WW + gc];
    P[r * PW + c] = v;
}

__device__ __forceinline__ float fract_f(float x) {
#if __has_builtin(__builtin_amdgcn_fractf)
    return __builtin_amdgcn_fractf(x);
#else
    return x - floorf(x);
#endif
}

// 16B load with only 4B-known alignment (c_lo is arbitrary); AMDGPU backend
// merges this into one global_load_dwordx4 (global unaligned access is legal).
__device__ __forceinline__ f32x4 load4(const float* p) {
    f32x4 v;
    __builtin_memcpy(&v, p, 16);
    return v;
}

struct BB {
    int c_lo, r_lo, bh;
    bool valid;
    float v0;
};

template <int STRIDE>
__device__ __forceinline__ void sample_chunk(
    const float* __restrict__ tb, const BB& b,
    const float s, const float c, const float u, const int wid,
    float& acc0, float& acc1)
{
    const float bc = fmaf(c, u, 255.5f - (float)b.c_lo);
    const float br = fmaf(-s, u, 255.5f - (float)b.r_lo);
    const float vy0 = b.v0 + (float)(wid * (YC / NW));

    f32x2 crx, stepv;
    crx.x = fmaf(s, vy0, bc);     // local col coord, >= 0
    crx.y = fmaf(c, vy0, br);     // local row coord, >= 0
    stepv.x = s;
    stepv.y = c;

#pragma unroll
    for (int i = 0; i < YC / NW; ++i) {
        const float cxl = crx.x;
        const float rxl = crx.y;
        const int ci = (int)cxl;             // == floor for >= 0
        const int ri = (int)rxl;
        const float wx1 = fract_f(cxl);
        const float wy1 = fract_f(rxl);

        __builtin_assume(ri >= 0 && ri < ROWS_MAX);
        __builtin_assume(ci >= 0 && ci < SMAX);
        const int ad = ri * STRIDE + ci;

        // two ds_read2_b32: (v00,v01) at dword offsets (0,1) and
        // (v10,v11) at (STRIDE,STRIDE+1) — immediates encodable
        f32x2 top, bot;
        top.x = tb[ad];
        top.y = tb[ad + 1];
        bot.x = tb[ad + STRIDE];
        bot.y = tb[ad + STRIDE + 1];

        f32x2 wyv;
        wyv.x = wy1;
        wyv.y = wy1;
        const f32x2 pv = __builtin_elementwise_fma(wyv, bot - top, top);

        acc0 += pv.x;
        acc1 = fmaf(wx1, pv.y - pv.x, acc1);

        crx += stepv;
    }
}

template <bool PADDED, int STRIDE>
__device__ __forceinline__ void radon_body(
    const float* __restrict__ src, float* __restrict__ tile,
    const float s, const float c, const int lane, const int wid, const int x0,
    const int tid, float& acc0, float& acc1)
{
    constexpr bool CPOS = (STRIDE == 95);   // stride picked by sign(c)

    const float u  = (float)(x0 + lane) + (0.5f - 256.0f);
    const float u0 = (float)x0 + (0.5f - 256.0f);
    const float u1 = u0 + (float)(XC - 1);

    // origin-shifted padded base: valid for row/col indices in [-PAD, WW+PAD)
    const float* __restrict__ Porg = PADDED ? (src + PAD * PW + PAD) : src;

    // sign(c) known at compile time (s >= 0 always): each bbox bound is one
    // affine expression — no fmin/fmax trees. (Verified on HW in round 3.)
    auto bbox = [&](int k) -> BB {
        BB b;
        b.v0 = (float)(k * YC) - 255.5f;
        const float v1 = b.v0 + (float)(YC - 1);
        float cx_min, cx_max, rx_min, rx_max;
        if (CPOS) {
            cx_min = fmaf(c, u0, fmaf(s, b.v0, 255.5f));
            cx_max = fmaf(c, u1, fmaf(s, v1,   255.5f));
            rx_min = fmaf(-s, u1, fmaf(c, b.v0, 255.5f));
            rx_max = fmaf(-s, u0, fmaf(c, v1,   255.5f));
        } else {
            cx_min = fmaf(c, u1, fmaf(s, b.v0, 255.5f));
            cx_max = fmaf(c, u0, fmaf(s, v1,   255.5f));
            rx_min = fmaf(-s, u1, fmaf(c, v1,   255.5f));
            rx_max = fmaf(-s, u0, fmaf(c, b.v0, 255.5f));
        }
        b.c_lo = (int)floorf(cx_min);
        b.r_lo = (int)floorf(rx_min);
        const int c_hi = (int)floorf(cx_max) + 1;
        const int r_hi = (int)floorf(rx_max) + 1;
        b.bh = min(r_hi - b.r_lo + 1, ROWS_MAX);
        b.valid = (b.c_lo <= WW - 1) & (c_hi >= 0) & (b.r_lo <= HH - 1) & (r_hi >= 0);
        return b;
    };

    if (PADDED) {
        // seg e in [0, bh*23): r = e/23 (magic mul, valid for e < 2116),
        // sseg = e - 23r. Global dword off = 4e + (PW-92)r; LDS dword off =
        // 4e + (STRIDE-92)r. All staged addresses lie inside the padded image
        // (row/col in [-106, 603] subset of [-112, 624)).
        f32x4 p[NSLOT];

        auto prefetch = [&](const BB& b) {
            const float* gb = Porg + b.r_lo * PW + b.c_lo;
            const int n = b.bh * SEGW;
#pragma unroll
            for (int i = 0; i < NSLOT; ++i) {
                const int e = tid + i * 512;
                if (e < n) {
                    const int r = (int)(((unsigned)(e * 2850)) >> 16);
                    p[i] = load4(gb + 4 * e + (PW - 4 * SEGW) * r);
                }
            }
        };

        auto write_tile = [&](const BB& b) {
            const int n = b.bh * SEGW;
#pragma unroll
            for (int i = 0; i < NSLOT; ++i) {
                const int e = tid + i * 512;
                if (e < n) {
                    const int r = (int)(((unsigned)(e * 2850)) >> 16);
                    const int o = 4 * e + (STRIDE - 4 * SEGW) * r;
                    tile[o]     = p[i].x;   // -> 2x ds_write2_b32
                    tile[o + 1] = p[i].y;
                    tile[o + 2] = p[i].z;
                    tile[o + 3] = p[i].w;
                }
            }
        };

        // ---- register-pipelined staging: loads(k+1) in flight during sample(k)
        BB cur = bbox(0);
        BB nxt = bbox(1);
        if (cur.valid) {
            prefetch(cur);
            write_tile(cur);           // vmcnt wait exposed once, at startup
        }
        if (nxt.valid) prefetch(nxt);  // in flight across sample(0)
        __syncthreads();

#pragma unroll 1
        for (int k = 0; k < NCH; ++k) {
            BB n2;
            n2.valid = false;
            if (k + 2 < NCH) n2 = bbox(k + 2);

            if (cur.valid)
                sample_chunk<STRIDE>(tile, cur, s, c, u, wid, acc0, acc1);

            __syncthreads();           // all waves done reading tile

            // regs loaded a full sample phase ago -> vmcnt wait ~free
            if (nxt.valid) write_tile(nxt);
            if (n2.valid)  prefetch(n2);   // in flight across sample(k+1)

            __syncthreads();           // tile(k+1) visible

            cur = nxt;
            nxt = n2;
        }
    } else {
        // fallback (no workspace): round-1 structure, direct LDS staging
#pragma unroll 1
        for (int k = 0; k < NCH; ++k) {
            BB b = bbox(k);
            if (!b.valid) { __syncthreads(); __syncthreads(); continue; }
            const int bw = SMAX;
            __syncthreads();
            for (int r = wid; r < b.bh; r += NW) {
                const int gr = b.r_lo + r;
                const bool row_ok = ((unsigned)gr < (unsigned)HH);
                const float* __restrict__ rowp = src + gr * WW;
                for (int cc = lane; cc < bw; cc += 64) {
                    const int gc = b.c_lo + cc;
                    float v = 0.0f;
                    if (row_ok) {
                        const int gcl = min(max(gc, 0), WW - 1);
                        const float t = rowp[gcl];
                        v = ((unsigned)gc < (unsigned)WW) ? t : 0.0f;
                    }
                    tile[r * STRIDE + cc] = v;
                }
            }
            __syncthreads();
            sample_chunk<STRIDE>(tile, b, s, c, u, wid, acc0, acc1);
        }
        __syncthreads();   // sampling done before epilogue reuses tile
    }
}

template <bool PADDED>
__global__ __launch_bounds__(512, 8) void radon_kernel(
    const float* __restrict__ src,   // PADDED ? padded image : raw image
    const float* __restrict__ angles, float* __restrict__ out)
{
    __shared__ float tile[ROWS_MAX * SMAX];   // 35.7 KB -> 4 blocks/CU (32 waves)

    const int tid  = threadIdx.x;
    const int lane = tid & 63;
    const int wid  = tid >> 6;     // 0..7

    const int a  = blockIdx.x >> 3;
    const int x0 = (blockIdx.x & 7) * XC;

    float s, c;
    sincosf(angles[a], &s, &c);

    // bank = (ri*stride + ci) % 32; stride 95 (== -1 mod 32) -> bank step c+s,
    // stride 97 (== +1) -> bank step c-s. s>=0: pick so |step| >= 1 always.
    // Block-uniform branch (same angle for whole block) -> __syncthreads safe.
    float acc0 = 0.0f, acc1 = 0.0f;
    if (c >= 0.0f)
        radon_body<PADDED, 95>(src, tile, s, c, lane, wid, x0, tid, acc0, acc1);
    else
        radon_body<PADDED, 97>(src, tile, s, c, lane, wid, x0, tid, acc0, acc1);

    // reduce the 8 y-groups per column and store (each block owns its outputs)
    __syncthreads();
    tile[tid] = acc0 + acc1;
    __syncthreads();
    if (tid < 64) {
        float r = tile[tid];
#pragma unroll
        for (int k = 1; k < NW; ++k) r += tile[k * 64 + tid];
        out[a * WW + x0 + tid] = r;
    }
}

extern "C" void kernel_launch(void* const* d_in, const int* in_sizes, int n_in,
                              void* d_out, int out_size, void* d_ws, size_t ws_size,
                              hipStream_t stream) {
    const float* img    = (const float*)d_in[0];
    const float* angles = (const float*)d_in[1];
    float* out = (float*)d_out;
    float* P   = (float*)d_ws;

    const bool padded = (ws_size >= (size_t)PW * PH * sizeof(float));

    if (padded) {
        pad_kernel<<<dim3((PW + 255) / 256, PH), 256, 0, stream>>>(img, P);
        radon_kernel<true><<<dim3(NA * NXC), 512, 0, stream>>>(P, angles, out);
    } else {
        radon_kernel<false><<<dim3(NA * NXC), 512, 0, stream>>>(img, angles, out);
    }
}

// Round 5
// 109.314 us; speedup vs baseline: 1.3597x; 1.3597x over previous
//
#include <hip/hip_runtime.h>

// Radon transform: data (1,1,512,512) f32, angles (256,) f32 -> out (1,1,256,512) f32.
// Block = (angle, 64-col x-chunk), 512 threads (8 waves). For each of 8 64-row
// y-chunks, stage the rotated patch's bbox (<=92x92) into a single 35.8 KB LDS
// buffer (4 blocks/CU = 32 waves = HW max; rounds 3/4 proved occupancy and the
// 64-VGPR budget are inviolable) and bilinear-sample from LDS. Staging reads a
// zero-PADDED image (d_ws) via global_load_lds width=16, one instr per bbox row.
// Sampling is ILP-BATCHED in groups of 4: addresses first, then all 8 ds_read2_b32
// issued together, then pure packed math -- LDS latency amortized per group, not
// per sample (round-1's VGPR=16 code serialized each sample on lgkmcnt).
// STRIDE 95/97 by sign(c), compile-time: per-lane bank step |c +- s| in [1,1.414]
// -> ~conflict-free; taps compile to ds_read2_b32 pairs (offsets 0,1 / 95,96).

#define HH 512
#define WW 512
#define NA 256
#define XC 64
#define YC 64
#define NXC (WW / XC)          // 8 x-chunks
#define NYC (HH / YC)          // 8 y-chunks
#define NW 8                   // waves per block
#define ROWS_MAX 92
#define SMAX 97
#define PAD 112                // >= 256*sqrt(2)-256+2
#define PW (WW + 2 * PAD)      // 736
#define PH (HH + 2 * PAD)      // 736

typedef float f32x2 __attribute__((ext_vector_type(2)));

__global__ __launch_bounds__(256) void pad_kernel(
    const float* __restrict__ img, float* __restrict__ P)
{
    const int c = blockIdx.x * 256 + threadIdx.x;
    const int r = blockIdx.y;
    if (c >= PW) return;
    const int gr = r - PAD, gc = c - PAD;
    float v = 0.0f;
    if ((unsigned)gr < (unsigned)HH && (unsigned)gc < (unsigned)WW)
        v = img[gr * WW + gc];
    P[r * PW + c] = v;
}

__device__ __forceinline__ float fract_f(float x) {
#if __has_builtin(__builtin_amdgcn_fractf)
    return __builtin_amdgcn_fractf(x);
#else
    return x - floorf(x);
#endif
}

template <int STRIDE>
__device__ __forceinline__ void sample_chunk(
    const float* __restrict__ tb, const int c_lo, const int r_lo, const float v0,
    const float s, const float c, const float u, const int wid, f32x2& acc)
{
    const float bc = fmaf(c, u, 255.5f - (float)c_lo);
    const float br = fmaf(-s, u, 255.5f - (float)r_lo);
    const float vy0 = v0 + (float)(wid * 8);

    f32x2 crx, stepv;
    crx.x = fmaf(s, vy0, bc);     // local col coord, >= 0
    crx.y = fmaf(c, vy0, br);     // local row coord, >= 0
    stepv.x = s;
    stepv.y = c;

    // 8 samples as 2 groups of 4: per group, compute 4 addresses, issue all
    // 8 ds_read2_b32 back-to-back, then pure VALU. All arrays statically
    // indexed after unroll -> registers (peak live ~50 VGPR, under the
    // 64-VGPR cap of __launch_bounds__(512,8); round-4 spill lesson).
#pragma unroll
    for (int g = 0; g < 2; ++g) {
        int ad[4];
        float wx1[4], wy1[4];
#pragma unroll
        for (int i = 0; i < 4; ++i) {
            const float cxl = crx.x;
            const float rxl = crx.y;
            const int ci = (int)cxl;             // == floor for >= 0
            const int ri = (int)rxl;
            wx1[i] = fract_f(cxl);
            wy1[i] = fract_f(rxl);
            __builtin_assume(ri >= 0 && ri < ROWS_MAX);
            __builtin_assume(ci >= 0 && ci < SMAX);
            ad[i] = ri * STRIDE + ci;
            crx += stepv;
        }

        f32x2 top[4], bot[4];
#pragma unroll
        for (int i = 0; i < 4; ++i) {
            // ds_read2_b32 offset0:0 offset1:1 and offset0:STRIDE offset1:STRIDE+1
            top[i].x = tb[ad[i]];
            top[i].y = tb[ad[i] + 1];
            bot[i].x = tb[ad[i] + STRIDE];
            bot[i].y = tb[ad[i] + STRIDE + 1];
        }

#pragma unroll
        for (int i = 0; i < 4; ++i) {
            f32x2 wyv;
            wyv.x = wy1[i];
            wyv.y = wy1[i];
            const f32x2 pv = __builtin_elementwise_fma(wyv, bot[i] - top[i], top[i]);
            f32x2 wxv;
            wxv.x = 1.0f - wx1[i];
            wxv.y = wx1[i];
            acc = __builtin_elementwise_fma(wxv, pv, acc);   // v_pk_fma_f32
        }
    }
}

template <bool PADDED, int STRIDE>
__device__ __forceinline__ void radon_body(
    const float* __restrict__ src, float* __restrict__ tile,
    const float s, const float c, const int lane, const int wid, const int x0,
    f32x2& acc)
{
    constexpr bool CPOS = (STRIDE == 95);   // stride picked by sign(c)

    const float u  = (float)(x0 + lane) + (0.5f - 256.0f);
    const float u0 = (float)x0 + (0.5f - 256.0f);
    const float u1 = u0 + (float)(XC - 1);

    // origin-shifted padded base: valid for row/col indices in [-PAD, WW+PAD)
    const float* __restrict__ Porg = PADDED ? (src + PAD * PW + PAD) : src;

    for (int yc = 0; yc < NYC; ++yc) {
        const float v0 = (float)(yc * YC) + (0.5f - 256.0f);
        const float v1 = v0 + (float)(YC - 1);

        // sign(c) known at compile time (s >= 0 always): each bbox bound is
        // one affine expression -- no fmin/fmax trees (HW-verified r3/r4).
        float cx_min, cx_max, rx_min, rx_max;
        if (CPOS) {
            cx_min = fmaf(c, u0, fmaf(s, v0, 255.5f));
            cx_max = fmaf(c, u1, fmaf(s, v1, 255.5f));
            rx_min = fmaf(-s, u1, fmaf(c, v0, 255.5f));
            rx_max = fmaf(-s, u0, fmaf(c, v1, 255.5f));
        } else {
            cx_min = fmaf(c, u1, fmaf(s, v0, 255.5f));
            cx_max = fmaf(c, u0, fmaf(s, v1, 255.5f));
            rx_min = fmaf(-s, u1, fmaf(c, v1, 255.5f));
            rx_max = fmaf(-s, u0, fmaf(c, v0, 255.5f));
        }

        const int c_lo = (int)floorf(cx_min);
        const int c_hi = (int)floorf(cx_max) + 1;
        const int r_lo = (int)floorf(rx_min);
        const int r_hi = (int)floorf(rx_max) + 1;
        const int bh = min(r_hi - r_lo + 1, ROWS_MAX);

        // chunk entirely outside image -> contributes exactly 0 (zero padding)
        if (c_lo > WW - 1 || c_hi < 0 || r_lo > HH - 1 || r_hi < 0) continue;

        __syncthreads();   // previous chunk's sampling must finish before overwrite

        if (PADDED) {
            // one global_load_lds_dwordx4 per bbox row: lanes 0..22 each move
            // 16 B -> LDS row base + lane*16 (368 B covers 92 dwords; <= STRIDE*4).
            // All staged addresses inside the padded image ([-106,617] in [-112,624)).
            if (lane < 23) {
                const float* g = Porg + (r_lo + wid) * PW + c_lo + lane * 4;
                float* l = &tile[wid * STRIDE];
                for (int r = wid; r < bh; r += NW) {
                    __builtin_amdgcn_global_load_lds(
                        (__attribute__((address_space(1))) const void*)g,
                        (__attribute__((address_space(3))) void*)l, 16, 0, 0);
                    g += NW * PW;
                    l += NW * STRIDE;
                }
            }
        } else {
            const int bw = min(c_hi - c_lo + 1, SMAX);
            for (int r = wid; r < bh; r += NW) {
                const int gr = r_lo + r;
                const bool row_ok = ((unsigned)gr < (unsigned)HH);
                const float* __restrict__ rowp = src + gr * WW;
                for (int cc = lane; cc < bw; cc += 64) {
                    const int gc = c_lo + cc;
                    float v = 0.0f;
                    if (row_ok) {
                        const int gcl = min(max(gc, 0), WW - 1);
                        const float t = rowp[gcl];
                        v = ((unsigned)gc < (unsigned)WW) ? t : 0.0f;
                    }
                    tile[r * STRIDE + cc] = v;
                }
            }
        }

        __syncthreads();

        sample_chunk<STRIDE>(tile, c_lo, r_lo, v0, s, c, u, wid, acc);
    }
}

template <bool PADDED>
__global__ __launch_bounds__(512, 8) void radon_kernel(
    const float* __restrict__ src,   // PADDED ? padded image : raw image
    const float* __restrict__ angles, float* __restrict__ out)
{
    __shared__ float tile[ROWS_MAX * SMAX];   // 35.7 KB -> 4 blocks/CU (32 waves)

    const int tid  = threadIdx.x;
    const int lane = tid & 63;
    const int wid  = tid >> 6;     // 0..7

    const int a  = blockIdx.x >> 3;
    const int x0 = (blockIdx.x & 7) * XC;

    float s, c;
    sincosf(angles[a], &s, &c);

    // bank = (ri*stride + ci) % 32; stride 95 (== -1 mod 32) -> bank step c+s,
    // stride 97 (== +1) -> bank step c-s. s>=0: pick so |step| >= 1 always.
    // Block-uniform branch (same angle for whole block) -> __syncthreads safe.
    f32x2 acc;
    acc.x = 0.0f;
    acc.y = 0.0f;
    if (c >= 0.0f)
        radon_body<PADDED, 95>(src, tile, s, c, lane, wid, x0, acc);
    else
        radon_body<PADDED, 97>(src, tile, s, c, lane, wid, x0, acc);

    // reduce the 8 y-groups per column and store (each block owns its outputs)
    __syncthreads();
    tile[tid] = acc.x + acc.y;
    __syncthreads();
    if (tid < 64) {
        float r = tile[tid];
#pragma unroll
        for (int k = 1; k < NW; ++k) r += tile[k * 64 + tid];
        out[a * WW + x0 + tid] = r;
    }
}

extern "C" void kernel_launch(void* const* d_in, const int* in_sizes, int n_in,
                              void* d_out, int out_size, void* d_ws, size_t ws_size,
                              hipStream_t stream) {
    const float* img    = (const float*)d_in[0];
    const float* angles = (const float*)d_in[1];
    float* out = (float*)d_out;
    float* P   = (float*)d_ws;

    const bool padded = (ws_size >= (size_t)PW * PH * sizeof(float));

    if (padded) {
        pad_kernel<<<dim3((PW + 255) / 256, PH), 256, 0, stream>>>(img, P);
        radon_kernel<true><<<dim3(NA * NXC), 512, 0, stream>>>(P, angles, out);
    } else {
        radon_kernel<false><<<dim3(NA * NXC), 512, 0, stream>>>(img, angles, out);
    }
}

// Round 7
// 108.074 us; speedup vs baseline: 1.3753x; 1.0115x over previous
//
#include <hip/hip_runtime.h>

// Radon transform: data (1,1,512,512) f32, angles (256,) f32 -> out (1,1,256,512) f32.
// Block = (angle, 64-col x-chunk), 512 threads (8 waves). For each of 8 64-row
// y-chunks, stage the rotated patch's bbox (<=92x92) into a single 35.8 KB LDS
// buffer (4 blocks/CU = 32 waves; rounds 3/4 proved occupancy + the 64-VGPR cap
// are inviolable) and bilinear-sample from LDS. Staging reads a zero-PADDED image
// (d_ws) via global_load_lds width=16, one instr per bbox row.
// r6/r7: sched_barrier(0) fences force each 4-sample group's 8 ds_read2_b32 to
// issue BEFORE any lerp math (r5's source intended this; VGPR=24 showed the
// scheduler re-serialized it). Rolling lgkmcnt waits + cross-group overlap
// (group g+1's addr VALU may schedule into group g's math region). Independent
// per-sample coords (fma from base, no serial DDA chain), split accumulators
// (halve the fma chain), s_setprio(1) around math (4 desynced blocks/CU).
// STRIDE 95/97 by sign(c), compile-time: per-lane bank step |c +- s| in [1,1.414].

#define HH 512
#define WW 512
#define NA 256
#define XC 64
#define YC 64
#define NXC (WW / XC)          // 8 x-chunks
#define NYC (HH / YC)          // 8 y-chunks
#define NW 8                   // waves per block
#define ROWS_MAX 92
#define SMAX 97
#define PAD 112                // >= 256*sqrt(2)-256+2
#define PW (WW + 2 * PAD)      // 736
#define PH (HH + 2 * PAD)      // 736

typedef float f32x2 __attribute__((ext_vector_type(2)));

__global__ __launch_bounds__(256) void pad_kernel(
    const float* __restrict__ img, float* __restrict__ P)
{
    const int c = blockIdx.x * 256 + threadIdx.x;
    const int r = blockIdx.y;
    if (c >= PW) return;
    const int gr = r - PAD, gc = c - PAD;
    float v = 0.0f;
    if ((unsigned)gr < (unsigned)HH && (unsigned)gc < (unsigned)WW)
        v = img[gr * WW + gc];
    P[r * PW + c] = v;
}

__device__ __forceinline__ float fract_f(float x) {
#if __has_builtin(__builtin_amdgcn_fractf)
    return __builtin_amdgcn_fractf(x);
#else
    return x - floorf(x);
#endif
}

template <int STRIDE>
__device__ __forceinline__ void sample_chunk(
    const float* __restrict__ tb, const int c_lo, const int r_lo, const float v0,
    const float s, const float c, const float u, const int wid,
    f32x2& accA, f32x2& accB)
{
    const float bc = fmaf(c, u, 255.5f - (float)c_lo);
    const float br = fmaf(-s, u, 255.5f - (float)r_lo);
    const float vy0 = v0 + (float)(wid * 8);

    f32x2 base, stepv;
    base.x = fmaf(s, vy0, bc);     // local col coord, >= 0
    base.y = fmaf(c, vy0, br);     // local row coord, >= 0
    stepv.x = s;
    stepv.y = c;

    f32x2 k2, k3, k4;
    k2.x = 2.0f; k2.y = 2.0f;
    k3.x = 3.0f; k3.y = 3.0f;
    k4.x = 4.0f; k4.y = 4.0f;

    // 8 samples as 2 groups of 4. Per group: 4 INDEPENDENT coord vectors
    // (fma from base -- no serial DDA chain), 4 addresses, then ALL 8
    // ds_read2_b32 issued back-to-back (sched_barrier pins read->math order),
    // then pure packed math. Group g+1's addr/read work may schedule into
    // group g's math region (fences are points, not ranges).
#pragma unroll
    for (int g = 0; g < 2; ++g) {
        f32x2 crs[4];
        crs[0] = base;
        crs[1] = base + stepv;
        crs[2] = __builtin_elementwise_fma(stepv, k2, base);
        crs[3] = __builtin_elementwise_fma(stepv, k3, base);
        base = __builtin_elementwise_fma(stepv, k4, base);

        int ad[4];
        float wx[4], wy[4];
#pragma unroll
        for (int i = 0; i < 4; ++i) {
            const int ci = (int)crs[i].x;        // == floor for >= 0
            const int ri = (int)crs[i].y;
            wx[i] = fract_f(crs[i].x);
            wy[i] = fract_f(crs[i].y);
            __builtin_assume(ri >= 0 && ri < ROWS_MAX);
            __builtin_assume(ci >= 0 && ci < SMAX);
            ad[i] = ri * STRIDE + ci;
        }

        f32x2 top[4], bot[4];
#pragma unroll
        for (int i = 0; i < 4; ++i) {
            // ds_read2_b32 (0,1) and (STRIDE,STRIDE+1) -- immediates encodable
            top[i].x = tb[ad[i]];
            top[i].y = tb[ad[i] + 1];
            bot[i].x = tb[ad[i] + STRIDE];
            bot[i].y = tb[ad[i] + STRIDE + 1];
        }
        // Fence: all 8 ds_read2 of this group issue before any of its math ->
        // waitcnt inserter emits rolling lgkmcnt(N) instead of per-sample waits.
        __builtin_amdgcn_sched_barrier(0);

        __builtin_amdgcn_s_setprio(1);
#pragma unroll
        for (int i = 0; i < 4; ++i) {
            f32x2 wyv;
            wyv.x = wy[i];
            wyv.y = wy[i];
            const f32x2 pv = __builtin_elementwise_fma(wyv, bot[i] - top[i], top[i]);
            f32x2 wxv;
            wxv.x = 1.0f - wx[i];
            wxv.y = wx[i];
            if (i & 1) accB = __builtin_elementwise_fma(wxv, pv, accB);
            else       accA = __builtin_elementwise_fma(wxv, pv, accA);
        }
        __builtin_amdgcn_s_setprio(0);
    }
}

template <bool PADDED, int STRIDE>
__device__ __forceinline__ void radon_body(
    const float* __restrict__ src, float* __restrict__ tile,
    const float s, const float c, const int lane, const int wid, const int x0,
    f32x2& accA, f32x2& accB)
{
    constexpr bool CPOS = (STRIDE == 95);   // stride picked by sign(c)

    const float u  = (float)(x0 + lane) + (0.5f - 256.0f);
    const float u0 = (float)x0 + (0.5f - 256.0f);
    const float u1 = u0 + (float)(XC - 1);

    // origin-shifted padded base: valid for row/col indices in [-PAD, WW+PAD)
    const float* __restrict__ Porg = PADDED ? (src + PAD * PW + PAD) : src;

    for (int yc = 0; yc < NYC; ++yc) {
        const float v0 = (float)(yc * YC) + (0.5f - 256.0f);
        const float v1 = v0 + (float)(YC - 1);

        // sign(c) known at compile time (s >= 0 always): each bbox bound is
        // one affine expression -- no fmin/fmax trees (HW-verified r3/r4).
        float cx_min, cx_max, rx_min, rx_max;
        if (CPOS) {
            cx_min = fmaf(c, u0, fmaf(s, v0, 255.5f));
            cx_max = fmaf(c, u1, fmaf(s, v1, 255.5f));
            rx_min = fmaf(-s, u1, fmaf(c, v0, 255.5f));
            rx_max = fmaf(-s, u0, fmaf(c, v1, 255.5f));
        } else {
            cx_min = fmaf(c, u1, fmaf(s, v0, 255.5f));
            cx_max = fmaf(c, u0, fmaf(s, v1, 255.5f));
            rx_min = fmaf(-s, u1, fmaf(c, v1, 255.5f));
            rx_max = fmaf(-s, u0, fmaf(c, v0, 255.5f));
        }

        const int c_lo = (int)floorf(cx_min);
        const int c_hi = (int)floorf(cx_max) + 1;
        const int r_lo = (int)floorf(rx_min);
        const int r_hi = (int)floorf(rx_max) + 1;
        const int bh = min(r_hi - r_lo + 1, ROWS_MAX);

        // chunk entirely outside image -> contributes exactly 0 (zero padding)
        if (c_lo > WW - 1 || c_hi < 0 || r_lo > HH - 1 || r_hi < 0) continue;

        __syncthreads();   // previous chunk's sampling must finish before overwrite

        if (PADDED) {
            // one global_load_lds_dwordx4 per bbox row: lanes 0..22 each move
            // 16 B -> LDS row base + lane*16 (368 B covers 92 dwords; <= STRIDE*4).
            // All staged addresses inside the padded image ([-106,617] in [-112,624)).
            if (lane < 23) {
                const float* g = Porg + (r_lo + wid) * PW + c_lo + lane * 4;
                float* l = &tile[wid * STRIDE];
                for (int r = wid; r < bh; r += NW) {
                    __builtin_amdgcn_global_load_lds(
                        (__attribute__((address_space(1))) const void*)g,
                        (__attribute__((address_space(3))) void*)l, 16, 0, 0);
                    g += NW * PW;
                    l += NW * STRIDE;
                }
            }
        } else {
            const int bw = min(c_hi - c_lo + 1, SMAX);
            for (int r = wid; r < bh; r += NW) {
                const int gr = r_lo + r;
                const bool row_ok = ((unsigned)gr < (unsigned)HH);
                const float* __restrict__ rowp = src + gr * WW;
                for (int cc = lane; cc < bw; cc += 64) {
                    const int gc = c_lo + cc;
                    float v = 0.0f;
                    if (row_ok) {
                        const int gcl = min(max(gc, 0), WW - 1);
                        const float t = rowp[gcl];
                        v = ((unsigned)gc < (unsigned)WW) ? t : 0.0f;
                    }
                    tile[r * STRIDE + cc] = v;
                }
            }
        }

        __syncthreads();

        sample_chunk<STRIDE>(tile, c_lo, r_lo, v0, s, c, u, wid, accA, accB);
    }
}

template <bool PADDED>
__global__ __launch_bounds__(512, 8) void radon_kernel(
    const float* __restrict__ src,   // PADDED ? padded image : raw image
    const float* __restrict__ angles, float* __restrict__ out)
{
    __shared__ float tile[ROWS_MAX * SMAX];   // 35.7 KB -> 4 blocks/CU (32 waves)

    const int tid  = threadIdx.x;
    const int lane = tid & 63;
    const int wid  = tid >> 6;     // 0..7

    const int a  = blockIdx.x >> 3;
    const int x0 = (blockIdx.x & 7) * XC;

    float s, c;
    sincosf(angles[a], &s, &c);

    // bank = (ri*stride + ci) % 32; stride 95 (== -1 mod 32) -> bank step c+s,
    // stride 97 (== +1) -> bank step c-s. s>=0: pick so |step| >= 1 always.
    // Block-uniform branch (same angle for whole block) -> __syncthreads safe.
    f32x2 accA, accB;
    accA.x = 0.0f; accA.y = 0.0f;
    accB.x = 0.0f; accB.y = 0.0f;
    if (c >= 0.0f)
        radon_body<PADDED, 95>(src, tile, s, c, lane, wid, x0, accA, accB);
    else
        radon_body<PADDED, 97>(src, tile, s, c, lane, wid, x0, accA, accB);

    // reduce the 8 y-groups per column and store (each block owns its outputs)
    __syncthreads();
    tile[tid] = (accA.x + accB.x) + (accA.y + accB.y);
    __syncthreads();
    if (tid < 64) {
        float r = tile[tid];
#pragma unroll
        for (int k = 1; k < NW; ++k) r += tile[k * 64 + tid];
        out[a * WW + x0 + tid] = r;
    }
}

extern "C" void kernel_launch(void* const* d_in, const int* in_sizes, int n_in,
                              void* d_out, int out_size, void* d_ws, size_t ws_size,
                              hipStream_t stream) {
    const float* img    = (const float*)d_in[0];
    const float* angles = (const float*)d_in[1];
    float* out = (float*)d_out;
    float* P   = (float*)d_ws;

    const bool padded = (ws_size >= (size_t)PW * PH * sizeof(float));

    if (padded) {
        pad_kernel<<<dim3((PW + 255) / 256, PH), 256, 0, stream>>>(img, P);
        radon_kernel<true><<<dim3(NA * NXC), 512, 0, stream>>>(P, angles, out);
    } else {
        radon_kernel<false><<<dim3(NA * NXC), 512, 0, stream>>>(img, angles, out);
    }
}